// Round 6
// baseline (853.554 us; speedup 1.0000x reference)
//
#include <hip/hip_runtime.h>

// Balanced sinkhorn, persistent kernel, round 11.
// R10 post-mortem: tag protocol cut poll flood ~30x and write traffic 3.5x
// yet phase cost stayed ~11-13us. Five structures (R5-R10) all land at
// 9.3-13.3us/phase => the invariant currency is the COUNT of serial
// cross-XCD handoffs (store -> CP-visible -> observe), ~1.3-1.6us each.
// R5 ~= 6 legs ~= 9.3us; R10 ~= 8 legs ~= 11-12us. Both fit.
// R11: leg-minimal 2-level tree, 4 legs, value-IS-the-signal (no tags,
// no critical-path drains):
//   leg1: member stores 2KB row -> group slab P[par][grp][rank][k]
//         (qNaN sentinel, parity-2)
//   leg2: owner (rank 0 of 16 per group) value-polls the 15 rows (each
//         element polled by exactly ONE thread machine-wide), restores NaN
//         (sole reader). Per-thread vmcnt(0) drain before its G2 store
//         orders restore vs the same thread's ph+2 republish — no
//         syncthreads needed (gating is per-element, per-thread).
//   leg3: owner stores group-sum row into per-phase-FRESH G2[48][16][256]
//         (write-once, read-only, no ABA, no restores)
//   leg4: all blocks value-poll 16 group rows, ascending sum (identical
//         deterministic total in every block -> replicated optimizer safe)
// All primitives R5-R10-proven; ONE structural change (R9 lesson).
// Phase math / LDS tiles / replicated optimizer identical to R3-R10
// (validated, absmax 2.4e-4; only fp64 summation association changes).

namespace {

constexpr int KDIM = 256;
constexpr int NBLK = 256;   // 1 block/CU, all co-resident (LDS-forced)
constexpr int ROWS = 64;    // rows per block
constexpr int NGRP = 16;    // groups (sqrt(256) balanced tree)
constexpr int GSZ  = 16;    // blocks per group
constexpr float L2E20 = 28.853900817779268f;  // 20 * log2(e)

// ws layout (doubles):
//   P [2][16][16][256]   131072  member rows (parity-2, owner-restored)
//   G2[48][16][256]      196608  group-sum rows (per-phase fresh)
constexpr size_t G2_OFF = 2ull * NGRP * GSZ * KDIM;     // 131072
constexpr size_t WS_DBL = G2_OFF + 48ull * NGRP * KDIM; // 327680 (2.62 MB)

__device__ __forceinline__ double fast_exp_d(double x) {
  const double LOG2E  = 1.4426950408889634074;
  const double LN2_HI = 6.93147180369123816490e-01;
  const double LN2_LO = 1.90821492927058770002e-10;
  double n = rint(x * LOG2E);
  double t = fma(-n, LN2_HI, x);
  t = fma(-n, LN2_LO, t);
  double p = 2.4801587301587302e-05;
  p = fma(p, t, 1.9841269841269841e-04);
  p = fma(p, t, 1.3888888888888889e-03);
  p = fma(p, t, 8.3333333333333333e-03);
  p = fma(p, t, 4.1666666666666664e-02);
  p = fma(p, t, 1.6666666666666666e-01);
  p = fma(p, t, 0.5);
  p = fma(p, t, 1.0);
  p = fma(p, t, 1.0);
  long long ni = (long long)n;
  double s = __longlong_as_double((unsigned long long)(ni + 1023LL) << 52);
  return p * s;
}

__device__ __forceinline__ double wave_sum_d(double v) {
#pragma unroll
  for (int o = 32; o > 0; o >>= 1) v += __shfl_down(v, o);
  return v;
}
__device__ __forceinline__ double wave_max_d(double v) {
#pragma unroll
  for (int o = 32; o > 0; o >>= 1) v = fmax(v, __shfl_down(v, o));
  return v;
}

__device__ __forceinline__ double pload(const double* p) {
  return __hip_atomic_load(p, __ATOMIC_RELAXED, __HIP_MEMORY_SCOPE_AGENT);
}
__device__ __forceinline__ void pstore(double* p, double v) {
  __hip_atomic_store(p, v, __ATOMIC_RELAXED, __HIP_MEMORY_SCOPE_AGENT);
}

}  // namespace

// ---------------------------------------------------------------------------
__global__ __launch_bounds__(256) void kInitWS(double* __restrict__ ws) {
  const double QN = __builtin_nan("");
  size_t gid = (size_t)blockIdx.x * 256 + threadIdx.x;
  size_t stride = (size_t)gridDim.x * 256;
  for (size_t j = gid; j < WS_DBL; j += stride) ws[j] = QN;
}

// ---------------------------------------------------------------------------
__global__ __launch_bounds__(256, 1) void sink_main(
    const float* __restrict__ feat, const float* __restrict__ w_in,
    float* __restrict__ out, double* __restrict__ ws) {
  __shared__ float  Et[ROWS * KDIM];   // 64 KB
  __shared__ float  Ft[ROWS * KDIM];   // 64 KB
  __shared__ double alpha[KDIM];
  __shared__ double v1s[ROWS], v2s[ROWS], v3s[ROWS];
  __shared__ double grow[ROWS], wrow[ROWS], sbr[ROWS];
  __shared__ float  mrow[ROWS];
  __shared__ double sred[8];

  const int t = threadIdx.x, bid = blockIdx.x;
  const int wv = t >> 6, lane = t & 63;
  const int b0 = bid * ROWS;
  const int grp = bid >> 4, rank = bid & 15;
  const double QN = __builtin_nan("");

  auto blk_sum = [&](double v) -> double {
    v = wave_sum_d(v);
    __syncthreads();
    if (lane == 0) sred[wv] = v;
    __syncthreads();
    return sred[0] + sred[1] + sred[2] + sred[3];
  };
  auto blk_max = [&](double v) -> double {
    v = wave_max_d(v);
    __syncthreads();
    if (lane == 0) sred[wv + 4] = v;
    __syncthreads();
    return fmax(fmax(sred[4], sred[5]), fmax(sred[6], sred[7]));
  };

  // ---- allreduce over blocks: thread t contributes pa for k=t,
  // returns the 256-block sum for k=t (identical in every block).
  auto allreduce = [&](unsigned ph, double pa) -> double {
    const int par = (int)(ph & 1);
    double* Pg  = ws + (((size_t)par * NGRP + grp) * GSZ) * KDIM;
    double* G2p = ws + G2_OFF + (size_t)ph * NGRP * KDIM;
    if (rank == 0) {
      // leg2: value-poll 15 member rows (sole reader per element)
      double v[GSZ - 1];
#pragma unroll
      for (int r = 0; r < GSZ - 1; ++r)
        v[r] = pload(Pg + (size_t)(r + 1) * KDIM + t);
      for (;;) {
        bool again = false;
#pragma unroll
        for (int r = 0; r < GSZ - 1; ++r)
          if (__builtin_isnan(v[r])) {
            v[r] = pload(Pg + (size_t)(r + 1) * KDIM + t);
            if (__builtin_isnan(v[r])) again = true;
          }
        if (!again) break;
        __builtin_amdgcn_s_sleep(1);
      }
      double acc = pa;
#pragma unroll
      for (int r = 0; r < GSZ - 1; ++r) acc += v[r];
      // restore sentinels (sole reader), drain, then signal via G2 value.
      // Per-thread ordering: this thread's ph+2 consumers transitively
      // depend on this G2 store, which follows the drain of the restores.
#pragma unroll
      for (int r = 0; r < GSZ - 1; ++r)
        pstore(Pg + (size_t)(r + 1) * KDIM + t, QN);
      asm volatile("s_waitcnt vmcnt(0)" ::: "memory");
      // leg3: publish group sum (per-phase fresh, value is the signal)
      pstore(G2p + (size_t)grp * KDIM + t, acc);
    } else {
      // leg1: publish member row (value is the signal)
      pstore(Pg + (size_t)rank * KDIM + t, pa);
    }
    // leg4: all blocks poll the 16 group rows, ascending deterministic sum
    double g[NGRP];
#pragma unroll
    for (int x = 0; x < NGRP; ++x) g[x] = pload(G2p + (size_t)x * KDIM + t);
    for (;;) {
      bool again = false;
#pragma unroll
      for (int x = 0; x < NGRP; ++x)
        if (__builtin_isnan(g[x])) {
          g[x] = pload(G2p + (size_t)x * KDIM + t);
          if (__builtin_isnan(g[x])) again = true;
        }
      if (!again) break;
      __builtin_amdgcn_s_sleep(4);
    }
    double tot = g[0];
#pragma unroll
    for (int x = 1; x < NGRP; ++x) tot += g[x];
    return tot;
  };

  auto row_pass = [&](double* dstv) {
    double a0 = alpha[4 * lane + 0], a1 = alpha[4 * lane + 1];
    double a2 = alpha[4 * lane + 2], a3 = alpha[4 * lane + 3];
#pragma unroll 4
    for (int r = wv; r < ROWS; r += 4) {
      float4 e4 = ((const float4*)(Et + r * KDIM))[lane];
      double s1 = a0 * (double)e4.x + a1 * (double)e4.y +
                  a2 * (double)e4.z + a3 * (double)e4.w;
      s1 = wave_sum_d(s1);
      if (lane == 0) dstv[r] = s1;
    }
  };
  auto col_partial = [&]() -> double {
    double a = 0.0;
#pragma unroll 8
    for (int r = 0; r < ROWS; ++r) a += (double)Et[r * KDIM + t] * wrow[r];
    return a;
  };

  // ================= setup =================
  {
    const float4* src = (const float4*)(feat + (size_t)b0 * KDIM);
    float4* dst = (float4*)Ft;
#pragma unroll
    for (int s = 0; s < 16; ++s) dst[s * 256 + t] = src[s * 256 + t];
  }
  __syncthreads();
  for (int r = wv; r < ROWS; r += 4) {
    float4 f4 = ((const float4*)(Ft + r * KDIM))[lane];
    float m = fmaxf(fmaxf(f4.x, f4.y), fmaxf(f4.z, f4.w));
#pragma unroll
    for (int o = 32; o > 0; o >>= 1) m = fmaxf(m, __shfl_down(m, o));
    if (lane == 0) {
      mrow[r] = m;
      sbr[r] = fast_exp_d(20.0 * (double)m);
    }
  }
  __syncthreads();
  double pu0 = 0.0;
#pragma unroll 8
  for (int r = 0; r < ROWS; ++r) {
    float e = exp2f((Ft[r * KDIM + t] - mrow[r]) * L2E20);
    Et[r * KDIM + t] = e;
    pu0 += (double)e * sbr[r];
  }
  float w_t = w_in[t], buf_t = 0.0f;
  double k2_t;
  {
    double x = (double)w_t;
    double m = blk_max(x);
    double e = fast_exp_d(x - m);
    double s = blk_sum(e);
    k2_t = e / s;
  }
  unsigned ph = 0;
  double u0_t = allreduce(ph, pu0);

  // ================= outer loop =================
  for (int it = 0; it < 10; ++it) {
    double u1_t, u2_t;

    // ---- A: v1~, allreduce u1
    alpha[t] = k2_t / u0_t;
    __syncthreads();
    row_pass(v1s);
    __syncthreads();
    if (t < ROWS) wrow[t] = 1.0 / (16384.0 * v1s[t]);
    __syncthreads();
    {
      double pa = col_partial();
      ++ph; u1_t = allreduce(ph, pa);
    }

    // ---- B: v2~, allreduce u2
    alpha[t] = k2_t / u1_t;
    __syncthreads();
    row_pass(v2s);
    __syncthreads();
    if (t < ROWS) wrow[t] = 1.0 / (16384.0 * v2s[t]);
    __syncthreads();
    {
      double pa = col_partial();
      ++ph; u2_t = allreduce(ph, pa);
    }

    if (it == 9) {
      // ---- output: Q[b,k] = alpha3[k]*E~[r,k]/v3~[b]
      alpha[t] = k2_t / u2_t;
      __syncthreads();
      row_pass(v3s);
      __syncthreads();
      if (t < ROWS) wrow[t] = 1.0 / v3s[t];
      __syncthreads();
      double a3 = alpha[t];
#pragma unroll 4
      for (int r = 0; r < ROWS; ++r)
        out[(size_t)(b0 + r) * KDIM + t] =
            (float)(a3 * (double)Et[r * KDIM + t] * wrow[r]);
      return;
    }

    // ---- C: v3~, gv3~; allreduce gsum = (gdir + t3)  [only the sum is used]
    alpha[t] = k2_t / u2_t;
    __syncthreads();
    {
      double a0 = alpha[4 * lane + 0], a1 = alpha[4 * lane + 1];
      double a2 = alpha[4 * lane + 2], a3 = alpha[4 * lane + 3];
#pragma unroll 2
      for (int r = wv; r < ROWS; r += 4) {
        float4 e4 = ((const float4*)(Et + r * KDIM))[lane];
        float4 f4 = ((const float4*)(Ft + r * KDIM))[lane];
        double p0 = a0 * (double)e4.x, p1 = a1 * (double)e4.y;
        double p2 = a2 * (double)e4.z, p3 = a3 * (double)e4.w;
        double s1 = p0 + p1 + p2 + p3;
        double s2 = p0 * (double)f4.x + p1 * (double)f4.y +
                    p2 * (double)f4.z + p3 * (double)f4.w;
        s1 = wave_sum_d(s1);
        s2 = wave_sum_d(s2);
        if (lane == 0) {
          v3s[r] = s1;
          grow[r] = s2 / (16384.0 * s1 * s1);  // gv3~
        }
      }
    }
    __syncthreads();
    if (t < ROWS) wrow[t] = -1.0 / (16384.0 * v3s[t]);
    __syncthreads();
    double gsum_t;
    {
      double ac1 = 0.0, ac2 = 0.0;
#pragma unroll 8
      for (int r = 0; r < ROWS; ++r) {
        double ed = (double)Et[r * KDIM + t];
        ac1 += ed * (double)Ft[r * KDIM + t] * wrow[r];
        ac2 += ed * grow[r];
      }
      ++ph; gsum_t = allreduce(ph, ac1 + ac2);
    }

    // ---- D: gu2 -> gv2~; allreduce ga2
    alpha[t] = -gsum_t * k2_t / (u2_t * u2_t);
    __syncthreads();
    row_pass(grow);
    __syncthreads();
    if (t < ROWS) wrow[t] = -grow[t] / (16384.0 * v2s[t] * v2s[t]);
    __syncthreads();
    double ga2_t;
    {
      double pa = col_partial();
      ++ph; ga2_t = allreduce(ph, pa);
    }

    // ---- E: gu1 -> gv1~; allreduce ga1
    alpha[t] = -ga2_t * k2_t / (u1_t * u1_t);
    __syncthreads();
    row_pass(grow);
    __syncthreads();
    if (t < ROWS) wrow[t] = -grow[t] / (16384.0 * v1s[t] * v1s[t]);
    __syncthreads();
    double ga1_t;
    {
      double pa = col_partial();
      ++ph; ga1_t = allreduce(ph, pa);
    }

    // ---- F: replicated optimizer step (block-local)
    {
      double gk2 = gsum_t / u2_t + ga2_t / u1_t + ga1_t / u0_t;
      double dot = blk_sum(k2_t * gk2);
      double gw = k2_t * (gk2 - dot) + 5.0 * (k2_t / 256.0 - 1.0 / 65536.0);
      double n2 = blk_sum(gw * gw);
      float normf = (float)sqrt(n2);
      float sc = fminf(1.0f, 1.0f / (normf + 1e-6f));
      float g = (float)gw * sc;
      buf_t = 0.99f * buf_t + g;
      w_t = w_t - 0.1f * buf_t;
      double x = (double)w_t;
      double m = blk_max(x);
      double e = fast_exp_d(x - m);
      double s = blk_sum(e);
      k2_t = e / s;
    }
  }
}

// ---------------------------------------------------------------------------
extern "C" void kernel_launch(void* const* d_in, const int* in_sizes, int n_in,
                              void* d_out, int out_size, void* d_ws,
                              size_t ws_size, hipStream_t stream) {
  (void)in_sizes; (void)n_in; (void)out_size; (void)ws_size;
  const float* feat = (const float*)d_in[0];
  const float* w_in = (const float*)d_in[1];
  float* out = (float*)d_out;
  double* ws = (double*)d_ws;

  kInitWS<<<128, 256, 0, stream>>>(ws);
  sink_main<<<NBLK, 256, 0, stream>>>(feat, w_in, out, ws);
}

// Round 7
// 638.603 us; speedup vs baseline: 1.3366x; 1.3366x over previous
//
#include <hip/hip_runtime.h>

// Balanced sinkhorn, persistent kernel, round 12.
// R11 post-mortem: 4-leg value-tree REGRESSED (17.2us/phase) because every
// poll was WIDE (all blocks re-poll 16x2KB group rows; owners poll 15 rows).
// Combined R5-R11 evidence: phase cost ~ legs x leg_latency, with
// leg_latency inflated by wide polling. Winning recipe: FEW LEGS + NARROW
// POLLS + ONE-SHOT WIDE READS. R5 (best, 10.5us) had narrow polls but 6
// legs (flag stores + drains). R12 hits the untried corner: 4 legs, all
// polls narrow:
//   leg1: all blocks publish 2KB partial row -> P[par][bid][k] (coalesced,
//         qNaN-sentinel, parity-2)
//   leg2: 16 reducer blocks (bid<16, reducer rid owns k in [16rid,16rid+16))
//         value-poll PER-ELEMENT: thread (seg,kl) polls P[par][16seg+j][k]
//         j=0..15 — each element polled by exactly ONE thread machine-wide;
//         only NaN elements re-polled (self-narrowing). Restores NaN after
//         capture; per-thread vmcnt(0) drain + the fold's __syncthreads
//         puts restore-visibility before the res publish (R5-validated
//         ordering; consumers are double-gated via res(ph+1) before any
//         ph+2 republish to this slab).
//   [LDS fold 16x16, deterministic ascending order -> identical result]
//   leg3: reducers publish result x16-replicated -> res[ph][rep][k]
//         (per-phase fresh, write-once; value IS the signal)
//   leg4: every block polls ONE element res[ph][bid&15][t] (R5-proven)
// Phase math / LDS tiles / replicated optimizer identical to R3-R11
// (validated, absmax 2.4e-4; only fp64 summation association changes).

namespace {

constexpr int KDIM = 256;
constexpr int NBLK = 256;   // 1 block/CU, all co-resident (LDS-forced)
constexpr int ROWS = 64;    // rows per block
constexpr int NRED = 16;    // reducer blocks
constexpr int NREP = 16;    // result replicas
constexpr int NPH  = 48;    // 1 + 9*5 + 2 allreduce phases
constexpr float L2E20 = 28.853900817779268f;  // 20 * log2(e)

// ws layout (doubles):
//   P  [2][256 blk][256 k]   131072  publish rows (parity-2, reducer-restored)
//   res[48 ph][16 rep][256 k] 196608 results (per-phase fresh, write-once)
constexpr size_t RES_OFF = 2ull * NBLK * KDIM;            // 131072
constexpr size_t WS_DBL  = RES_OFF + (size_t)NPH * NREP * KDIM;  // 327680

__device__ __forceinline__ double fast_exp_d(double x) {
  const double LOG2E  = 1.4426950408889634074;
  const double LN2_HI = 6.93147180369123816490e-01;
  const double LN2_LO = 1.90821492927058770002e-10;
  double n = rint(x * LOG2E);
  double t = fma(-n, LN2_HI, x);
  t = fma(-n, LN2_LO, t);
  double p = 2.4801587301587302e-05;
  p = fma(p, t, 1.9841269841269841e-04);
  p = fma(p, t, 1.3888888888888889e-03);
  p = fma(p, t, 8.3333333333333333e-03);
  p = fma(p, t, 4.1666666666666664e-02);
  p = fma(p, t, 1.6666666666666666e-01);
  p = fma(p, t, 0.5);
  p = fma(p, t, 1.0);
  p = fma(p, t, 1.0);
  long long ni = (long long)n;
  double s = __longlong_as_double((unsigned long long)(ni + 1023LL) << 52);
  return p * s;
}

__device__ __forceinline__ double wave_sum_d(double v) {
#pragma unroll
  for (int o = 32; o > 0; o >>= 1) v += __shfl_down(v, o);
  return v;
}
__device__ __forceinline__ double wave_max_d(double v) {
#pragma unroll
  for (int o = 32; o > 0; o >>= 1) v = fmax(v, __shfl_down(v, o));
  return v;
}

__device__ __forceinline__ double pload(const double* p) {
  return __hip_atomic_load(p, __ATOMIC_RELAXED, __HIP_MEMORY_SCOPE_AGENT);
}
__device__ __forceinline__ void pstore(double* p, double v) {
  __hip_atomic_store(p, v, __ATOMIC_RELAXED, __HIP_MEMORY_SCOPE_AGENT);
}

}  // namespace

// ---------------------------------------------------------------------------
__global__ __launch_bounds__(256) void kInitWS(double* __restrict__ ws) {
  const double QN = __builtin_nan("");
  size_t gid = (size_t)blockIdx.x * 256 + threadIdx.x;
  size_t stride = (size_t)gridDim.x * 256;
  for (size_t j = gid; j < WS_DBL; j += stride) ws[j] = QN;
}

// ---------------------------------------------------------------------------
__global__ __launch_bounds__(256, 1) void sink_main(
    const float* __restrict__ feat, const float* __restrict__ w_in,
    float* __restrict__ out, double* __restrict__ ws) {
  __shared__ float  Et[ROWS * KDIM];   // 64 KB
  __shared__ float  Ft[ROWS * KDIM];   // 64 KB
  __shared__ double alpha[KDIM];
  __shared__ double tmp1[KDIM];        // reducer fold stage 1
  __shared__ double sfin[16];          // reducer fold stage 2
  __shared__ double v1s[ROWS], v2s[ROWS], v3s[ROWS];
  __shared__ double grow[ROWS], wrow[ROWS], sbr[ROWS];
  __shared__ float  mrow[ROWS];
  __shared__ double sred[8];

  const int t = threadIdx.x, bid = blockIdx.x;
  const int wv = t >> 6, lane = t & 63;
  const int b0 = bid * ROWS;
  const double QN = __builtin_nan("");

  double* P   = ws;
  double* res = ws + RES_OFF;

  auto blk_sum = [&](double v) -> double {
    v = wave_sum_d(v);
    __syncthreads();
    if (lane == 0) sred[wv] = v;
    __syncthreads();
    return sred[0] + sred[1] + sred[2] + sred[3];
  };
  auto blk_max = [&](double v) -> double {
    v = wave_max_d(v);
    __syncthreads();
    if (lane == 0) sred[wv + 4] = v;
    __syncthreads();
    return fmax(fmax(sred[4], sred[5]), fmax(sred[6], sred[7]));
  };

  // ---- allreduce over blocks: thread t contributes pa for k=t,
  // returns the 256-block sum for k=t (identical in every block).
  auto allreduce = [&](unsigned ph, double pa) -> double {
    const int par = (int)(ph & 1);
    double* Pp = P + (size_t)par * NBLK * KDIM;
    double* R  = res + (size_t)ph * NREP * KDIM;
    // leg1: publish own row (coalesced 2KB; value is the signal)
    pstore(Pp + (size_t)bid * KDIM + t, pa);
    if (bid < NRED) {
      // leg2: per-element value-poll. Reducer bid owns k in [16bid,16bid+16).
      // Thread (seg=t>>4, kl=t&15) polls rows 16seg..16seg+15 at k=16bid+kl.
      const int kl = t & 15, seg = t >> 4;
      const int k = bid * 16 + kl;
      double* base = Pp + (size_t)(seg * 16) * KDIM + k;
      double v[16];
#pragma unroll
      for (int j = 0; j < 16; ++j) v[j] = pload(base + (size_t)j * KDIM);
      for (;;) {
        bool again = false;
#pragma unroll
        for (int j = 0; j < 16; ++j)
          if (__builtin_isnan(v[j])) {
            v[j] = pload(base + (size_t)j * KDIM);
            if (__builtin_isnan(v[j])) again = true;
          }
        if (!again) break;
        __builtin_amdgcn_s_sleep(1);
      }
      double a = 0.0;
#pragma unroll
      for (int j = 0; j < 16; ++j) a += v[j];   // ascending j: deterministic
      // restore sentinels (sole reader per element), drain own stores
#pragma unroll
      for (int j = 0; j < 16; ++j) pstore(base + (size_t)j * KDIM, QN);
      asm volatile("s_waitcnt vmcnt(0)" ::: "memory");
      tmp1[t] = a;
      __syncthreads();  // all threads' restores drained + tmp1 visible
      if (t < 16) {
        double s = 0.0;
#pragma unroll
        for (int sg = 0; sg < 16; ++sg) s += tmp1[sg * 16 + t];  // ascending
        sfin[t] = s;
      }
      __syncthreads();
      // leg3: publish x16-replicated result (per-phase fresh slab)
      pstore(R + (size_t)seg * KDIM + k, sfin[kl]);
    }
    // leg4: every block polls ONE element of its replica row
    const double* re = R + (size_t)(bid & (NREP - 1)) * KDIM + t;
    double r = pload(re);
    while (__builtin_isnan(r)) {
      __builtin_amdgcn_s_sleep(1);
      r = pload(re);
    }
    return r;
  };

  auto row_pass = [&](double* dstv) {
    double a0 = alpha[4 * lane + 0], a1 = alpha[4 * lane + 1];
    double a2 = alpha[4 * lane + 2], a3 = alpha[4 * lane + 3];
#pragma unroll 4
    for (int r = wv; r < ROWS; r += 4) {
      float4 e4 = ((const float4*)(Et + r * KDIM))[lane];
      double s1 = a0 * (double)e4.x + a1 * (double)e4.y +
                  a2 * (double)e4.z + a3 * (double)e4.w;
      s1 = wave_sum_d(s1);
      if (lane == 0) dstv[r] = s1;
    }
  };
  auto col_partial = [&]() -> double {
    double a = 0.0;
#pragma unroll 8
    for (int r = 0; r < ROWS; ++r) a += (double)Et[r * KDIM + t] * wrow[r];
    return a;
  };

  // ================= setup =================
  {
    const float4* src = (const float4*)(feat + (size_t)b0 * KDIM);
    float4* dst = (float4*)Ft;
#pragma unroll
    for (int s = 0; s < 16; ++s) dst[s * 256 + t] = src[s * 256 + t];
  }
  __syncthreads();
  for (int r = wv; r < ROWS; r += 4) {
    float4 f4 = ((const float4*)(Ft + r * KDIM))[lane];
    float m = fmaxf(fmaxf(f4.x, f4.y), fmaxf(f4.z, f4.w));
#pragma unroll
    for (int o = 32; o > 0; o >>= 1) m = fmaxf(m, __shfl_down(m, o));
    if (lane == 0) {
      mrow[r] = m;
      sbr[r] = fast_exp_d(20.0 * (double)m);
    }
  }
  __syncthreads();
  double pu0 = 0.0;
#pragma unroll 8
  for (int r = 0; r < ROWS; ++r) {
    float e = exp2f((Ft[r * KDIM + t] - mrow[r]) * L2E20);
    Et[r * KDIM + t] = e;
    pu0 += (double)e * sbr[r];
  }
  float w_t = w_in[t], buf_t = 0.0f;
  double k2_t;
  {
    double x = (double)w_t;
    double m = blk_max(x);
    double e = fast_exp_d(x - m);
    double s = blk_sum(e);
    k2_t = e / s;
  }
  unsigned ph = 0;
  double u0_t = allreduce(ph, pu0);

  // ================= outer loop =================
  for (int it = 0; it < 10; ++it) {
    double u1_t, u2_t;

    // ---- A: v1~, allreduce u1
    alpha[t] = k2_t / u0_t;
    __syncthreads();
    row_pass(v1s);
    __syncthreads();
    if (t < ROWS) wrow[t] = 1.0 / (16384.0 * v1s[t]);
    __syncthreads();
    {
      double pa = col_partial();
      ++ph; u1_t = allreduce(ph, pa);
    }

    // ---- B: v2~, allreduce u2
    alpha[t] = k2_t / u1_t;
    __syncthreads();
    row_pass(v2s);
    __syncthreads();
    if (t < ROWS) wrow[t] = 1.0 / (16384.0 * v2s[t]);
    __syncthreads();
    {
      double pa = col_partial();
      ++ph; u2_t = allreduce(ph, pa);
    }

    if (it == 9) {
      // ---- output: Q[b,k] = alpha3[k]*E~[r,k]/v3~[b]
      alpha[t] = k2_t / u2_t;
      __syncthreads();
      row_pass(v3s);
      __syncthreads();
      if (t < ROWS) wrow[t] = 1.0 / v3s[t];
      __syncthreads();
      double a3 = alpha[t];
#pragma unroll 4
      for (int r = 0; r < ROWS; ++r)
        out[(size_t)(b0 + r) * KDIM + t] =
            (float)(a3 * (double)Et[r * KDIM + t] * wrow[r]);
      return;
    }

    // ---- C: v3~, gv3~; allreduce gsum = (gdir + t3)  [only the sum is used]
    alpha[t] = k2_t / u2_t;
    __syncthreads();
    {
      double a0 = alpha[4 * lane + 0], a1 = alpha[4 * lane + 1];
      double a2 = alpha[4 * lane + 2], a3 = alpha[4 * lane + 3];
#pragma unroll 2
      for (int r = wv; r < ROWS; r += 4) {
        float4 e4 = ((const float4*)(Et + r * KDIM))[lane];
        float4 f4 = ((const float4*)(Ft + r * KDIM))[lane];
        double p0 = a0 * (double)e4.x, p1 = a1 * (double)e4.y;
        double p2 = a2 * (double)e4.z, p3 = a3 * (double)e4.w;
        double s1 = p0 + p1 + p2 + p3;
        double s2 = p0 * (double)f4.x + p1 * (double)f4.y +
                    p2 * (double)f4.z + p3 * (double)f4.w;
        s1 = wave_sum_d(s1);
        s2 = wave_sum_d(s2);
        if (lane == 0) {
          v3s[r] = s1;
          grow[r] = s2 / (16384.0 * s1 * s1);  // gv3~
        }
      }
    }
    __syncthreads();
    if (t < ROWS) wrow[t] = -1.0 / (16384.0 * v3s[t]);
    __syncthreads();
    double gsum_t;
    {
      double ac1 = 0.0, ac2 = 0.0;
#pragma unroll 8
      for (int r = 0; r < ROWS; ++r) {
        double ed = (double)Et[r * KDIM + t];
        ac1 += ed * (double)Ft[r * KDIM + t] * wrow[r];
        ac2 += ed * grow[r];
      }
      ++ph; gsum_t = allreduce(ph, ac1 + ac2);
    }

    // ---- D: gu2 -> gv2~; allreduce ga2
    alpha[t] = -gsum_t * k2_t / (u2_t * u2_t);
    __syncthreads();
    row_pass(grow);
    __syncthreads();
    if (t < ROWS) wrow[t] = -grow[t] / (16384.0 * v2s[t] * v2s[t]);
    __syncthreads();
    double ga2_t;
    {
      double pa = col_partial();
      ++ph; ga2_t = allreduce(ph, pa);
    }

    // ---- E: gu1 -> gv1~; allreduce ga1
    alpha[t] = -ga2_t * k2_t / (u1_t * u1_t);
    __syncthreads();
    row_pass(grow);
    __syncthreads();
    if (t < ROWS) wrow[t] = -grow[t] / (16384.0 * v1s[t] * v1s[t]);
    __syncthreads();
    double ga1_t;
    {
      double pa = col_partial();
      ++ph; ga1_t = allreduce(ph, pa);
    }

    // ---- F: replicated optimizer step (block-local)
    {
      double gk2 = gsum_t / u2_t + ga2_t / u1_t + ga1_t / u0_t;
      double dot = blk_sum(k2_t * gk2);
      double gw = k2_t * (gk2 - dot) + 5.0 * (k2_t / 256.0 - 1.0 / 65536.0);
      double n2 = blk_sum(gw * gw);
      float normf = (float)sqrt(n2);
      float sc = fminf(1.0f, 1.0f / (normf + 1e-6f));
      float g = (float)gw * sc;
      buf_t = 0.99f * buf_t + g;
      w_t = w_t - 0.1f * buf_t;
      double x = (double)w_t;
      double m = blk_max(x);
      double e = fast_exp_d(x - m);
      double s = blk_sum(e);
      k2_t = e / s;
    }
  }
}

// ---------------------------------------------------------------------------
extern "C" void kernel_launch(void* const* d_in, const int* in_sizes, int n_in,
                              void* d_out, int out_size, void* d_ws,
                              size_t ws_size, hipStream_t stream) {
  (void)in_sizes; (void)n_in; (void)out_size; (void)ws_size;
  const float* feat = (const float*)d_in[0];
  const float* w_in = (const float*)d_in[1];
  float* out = (float*)d_out;
  double* ws = (double*)d_ws;

  kInitWS<<<128, 256, 0, stream>>>(ws);
  sink_main<<<NBLK, 256, 0, stream>>>(feat, w_in, out, ws);
}